// Round 6
// baseline (347.720 us; speedup 1.0000x reference)
//
#include <hip/hip_runtime.h>

// rep config: E edges, D_IN = D_OUT = 4, M = 32 channels.
// out[e,o,m] = (sum_i basis[e,o,i] * nf[U[e],i,m]) * ew[e, (o==0?0:1), m]
//
// R5 diagnostic: FETCH ~= mandatory (285 MB single-pass), WRITE exact, VALU 8%,
// occ 86% -> limiter is TOTAL memory-system service BW (~7.1 TB/s incl. 385 MB
// of L3-served gather hits; per-XCD L2 holds only ~16% of the 25.6 MB table).
//
// R6: node-range multi-pass. 13 sequential pass-segments in one linearized
// grid; pass p handles only edges whose source node is in [p*4096,(p+1)*4096)
// (2 MB of nf <= 4 MiB per-XCD L2). Blocks dispatch in ascending blockIdx.x,
// so resident blocks share one ~2 MB nf window -> gathers hit L2 (free),
// removing ~385 MB of L3 service. Streams are read/written sparsely (1/13,
// ascending, full lines, each line in exactly one pass). nt on single-use
// streams (basis/ew loads, out stores) keeps L2 for nf + U.

typedef float f4 __attribute__((ext_vector_type(4)));

#define NSHIFT 12               // 4096 nodes per range -> 2 MB nf window
#define EDGES_PER_BLOCK 256     // 32 groups x 8 chunk-iterations

__global__ __launch_bounds__(256) void equiv_mm_pass_kernel(
    const float* __restrict__ basis,   // [E,4,4]
    const float* __restrict__ ew,      // [E,2,32]
    const float* __restrict__ nf,      // [N,4,32]
    const int*   __restrict__ U,       // [E]
    float*       __restrict__ out,     // [E,4,32]
    int E, int blocksPerPass)
{
    const int pass  = blockIdx.x / blocksPerPass;      // sequential segments
    const int blk   = blockIdx.x % blocksPerPass;
    const int group = threadIdx.x >> 3;                // 0..31
    const int m0    = (threadIdx.x & 7) << 2;          // 0,4,...,28
    const int ebase = blk * EDGES_PER_BLOCK;

    #pragma unroll 1
    for (int it = 0; it < 8; ++it) {
        int e = ebase + it * 32 + group;
        int u = 0;
        bool active = false;
        if (e < E) {
            u = U[e];                        // 32 consecutive ints per wave
            active = ((u >> NSHIFT) == pass);
        }
        // whole-wave skip: ~53% of wave-iterations have no active group
        if (__ballot(active) == 0ull) continue;
        if (!active) continue;

        // gather source-node features (normal loads; L2-window resident)
        const f4* xp = (const f4*)(nf + (size_t)u * 128 + m0);
        f4 x0 = xp[0];
        f4 x1 = xp[8];
        f4 x2 = xp[16];
        f4 x3 = xp[24];

        // per-edge 4x4 basis, single-use stream -> nontemporal
        const f4* bp = (const f4*)(basis + (size_t)e * 16);
        f4 b0 = __builtin_nontemporal_load(bp + 0);
        f4 b1 = __builtin_nontemporal_load(bp + 1);
        f4 b2 = __builtin_nontemporal_load(bp + 2);
        f4 b3 = __builtin_nontemporal_load(bp + 3);

        // radial weights, single-use stream -> nontemporal
        const f4* wp = (const f4*)(ew + (size_t)e * 64 + m0);
        f4 w0 = __builtin_nontemporal_load(wp + 0);
        f4 w1 = __builtin_nontemporal_load(wp + 8);

        // write-only output stream -> nontemporal
        f4* op = (f4*)(out + (size_t)e * 128 + m0);
        __builtin_nontemporal_store((b0.x * x0 + b0.y * x1 + b0.z * x2 + b0.w * x3) * w0, op + 0);
        __builtin_nontemporal_store((b1.x * x0 + b1.y * x1 + b1.z * x2 + b1.w * x3) * w1, op + 8);
        __builtin_nontemporal_store((b2.x * x0 + b2.y * x1 + b2.z * x2 + b2.w * x3) * w1, op + 16);
        __builtin_nontemporal_store((b3.x * x0 + b3.y * x1 + b3.z * x2 + b3.w * x3) * w1, op + 24);
    }
}

extern "C" void kernel_launch(void* const* d_in, const int* in_sizes, int n_in,
                              void* d_out, int out_size, void* d_ws, size_t ws_size,
                              hipStream_t stream) {
    const float* basis = (const float*)d_in[0];   // [E,4,4]
    const float* ew    = (const float*)d_in[1];   // [E,2,32]
    const float* nf    = (const float*)d_in[2];   // [N,4,32]
    const int*   U     = (const int*)d_in[3];     // [E]
    float* out = (float*)d_out;

    int E = in_sizes[0] / 16;
    int N = in_sizes[2] / 128;                    // nodes
    int npass = ((N - 1) >> NSHIFT) + 1;          // 13 for N=50000
    int blocksPerPass = (E + EDGES_PER_BLOCK - 1) / EDGES_PER_BLOCK;  // 3125
    int grid = blocksPerPass * npass;             // 40625 blocks, x-ascending

    equiv_mm_pass_kernel<<<grid, 256, 0, stream>>>(basis, ew, nf, U, out,
                                                   E, blocksPerPass);
}